// Round 20
// baseline (402.617 us; speedup 1.0000x reference)
//
#include <hip/hip_runtime.h>
#include <hip/hip_bf16.h>

#define NATOMS 20000
#define NEDGES 640000
#define HID 128
#define EDIM 64
#define NTILES (NEDGES / 64)   // 10000
#define K3TILES ((NATOMS + 63) / 64)  // 313

#define SCAN_BLOCKS 80
#define SCAN_CHUNK 250         // 80*250 = 20000

typedef __attribute__((ext_vector_type(8))) short bf16x8;
typedef __attribute__((ext_vector_type(4))) float f32x4;

__device__ __forceinline__ unsigned short f2b(float f) {
  union { float f; unsigned u; } c; c.f = f;
  unsigned u = c.u + 0x7fff + ((c.u >> 16) & 1);   // RNE (finite data)
  return (unsigned short)(u >> 16);
}

// pack 8 f32 -> 8 bf16 (HW v_cvt_pk_bf16_f32) and write 16B to LDS
__device__ __forceinline__ void write8(unsigned short* p, float4 a, float4 b) {
  union { __hip_bfloat162 h[4]; uint4 q; } pk;
  pk.h[0] = __float22bfloat162_rn(make_float2(a.x, a.y));
  pk.h[1] = __float22bfloat162_rn(make_float2(a.z, a.w));
  pk.h[2] = __float22bfloat162_rn(make_float2(b.x, b.y));
  pk.h[3] = __float22bfloat162_rn(make_float2(b.z, b.w));
  *(uint4*)p = pk.q;
}

// pack 8 f32 -> bf16x8 fragment in registers
__device__ __forceinline__ bf16x8 cvt8(float4 a, float4 b) {
  union { __hip_bfloat162 h[4]; bf16x8 v; } pk;
  pk.h[0] = __float22bfloat162_rn(make_float2(a.x, a.y));
  pk.h[1] = __float22bfloat162_rn(make_float2(a.z, a.w));
  pk.h[2] = __float22bfloat162_rn(make_float2(b.x, b.y));
  pk.h[3] = __float22bfloat162_rn(make_float2(b.z, b.w));
  return pk.v;
}

// Per-wave W fragments: wave owns cols [wbase, wbase+32). W fp32 [K][128].
template <int KSTEPS>
__device__ __forceinline__ void load_w(const float* __restrict__ W, int wbase,
                                       int lane, bf16x8 B[KSTEPS][2]) {
  const int col0 = wbase + (lane & 15);
  const int krow0 = (lane >> 4) * 8;
  #pragma unroll
  for (int ks = 0; ks < KSTEPS; ++ks)
    #pragma unroll
    for (int ni = 0; ni < 2; ++ni) {
      const float* p = W + (long long)(ks * 32 + krow0) * HID + col0 + ni * 16;
      bf16x8 b;
      #pragma unroll
      for (int j = 0; j < 8; ++j) b[j] = (short)f2b(p[(long long)j * HID]);
      B[ks][ni] = b;
    }
}

// ---------------- CSR build (rank-based; k_fill has NO atomics) --------------
__global__ __launch_bounds__(256) void k_hist(const int* __restrict__ dst,
                                              int* __restrict__ hist,
                                              float4* __restrict__ aggz,
                                              int* __restrict__ rank) {
  int e = blockIdx.x * 256 + threadIdx.x;
  if (e < NEDGES) {
    aggz[e] = make_float4(0.f, 0.f, 0.f, 0.f);
    rank[e] = atomicAdd(&hist[dst[e]], 1);
  }
}

// partial sums per 250-chunk
__global__ __launch_bounds__(256) void k_scan1(const int* __restrict__ hist,
                                               int* __restrict__ bsum) {
  __shared__ int sh[256];
  const int b = blockIdx.x, t = threadIdx.x;
  const int lo = b * SCAN_CHUNK;
  int s = 0;
  for (int i = t; i < SCAN_CHUNK; i += 256) s += hist[lo + i];
  sh[t] = s; __syncthreads();
  for (int off = 128; off > 0; off >>= 1) {
    if (t < off) sh[t] += sh[t + off];
    __syncthreads();
  }
  if (t == 0) bsum[b] = sh[0];
}

// per-block: base = sum(bsum[0..b)) computed redundantly; local scan -> cursor
__global__ __launch_bounds__(256) void k_scan3(const int* __restrict__ hist,
                                               const int* __restrict__ bsum,
                                               int* __restrict__ cursor) {
  __shared__ int sh[256];
  const int b = blockIdx.x, t = threadIdx.x;
  const int lo = b * SCAN_CHUNK;
  int v = (t < SCAN_BLOCKS && t < b) ? bsum[t] : 0;
  sh[t] = v; __syncthreads();
  for (int off = 128; off > 0; off >>= 1) {
    if (t < off) sh[t] += sh[t + off];
    __syncthreads();
  }
  const int blockoff = sh[0];
  __syncthreads();
  sh[t] = (t < SCAN_CHUNK) ? hist[lo + t] : 0;
  __syncthreads();
  for (int off = 1; off < 256; off <<= 1) {
    int u = (t >= off) ? sh[t - off] : 0;
    __syncthreads();
    sh[t] += u;
    __syncthreads();
  }
  if (t < SCAN_CHUNK) cursor[lo + t] = blockoff + ((t == 0) ? 0 : sh[t - 1]);
}

// fill dst-sorted packed (edge, src, dst) records — atomic-free
__global__ __launch_bounds__(256) void k_fill(const int* __restrict__ ei,
                                              const int* __restrict__ cursor,
                                              const int* __restrict__ rank,
                                              int4* __restrict__ esd) {
  int e = blockIdx.x * 256 + threadIdx.x;
  if (e < NEDGES) {
    const int s = ei[e];
    const int d = ei[NEDGES + e];
    const int p = cursor[d] + rank[e];
    esd[p] = make_int4(e, s, d, 0);
  }
}

// ---- K1 fused (R11-proven): per sorted-edge tile, m = relu([h_v[src]|ea]@W_i)
//      in LDS, per-WAVE private M tile -> same-wave segment-sum -> atomics. --
#define A1_ST 200   // bf16 staging row stride
#define MW_ST 33    // per-wave f32 M stride ([64][33])
#define MW_SZ (64 * MW_ST)
#define K1_SMEM (4 * MW_SZ * 4)     // 33792 B (A 25600 B overlaid)

__global__ __launch_bounds__(256, 3) void k1_fused(
    const float* __restrict__ h_v, const float* __restrict__ edge_attr,
    const float* __restrict__ W_i, const int4* __restrict__ esd,
    float* __restrict__ agg)
{
  __shared__ __align__(16) char smem[K1_SMEM];
  unsigned short* A = (unsigned short*)smem;
  float* M = (float*)smem;
  __shared__ int dstl[64];

  const int t = threadIdx.x, lane = t & 63, w = t >> 6;

  bf16x8 B[6][2];
  load_w<6>(W_i, w * 32, lane, B);

  for (int tile = blockIdx.x; tile < NTILES; tile += gridDim.x) {
    const int ebase = tile * 64;
    const int4 rec = esd[ebase + lane];        // (e, src, dst, _) coalesced
    if (w == 0) dstl[lane] = rec.z;
    {
      const float* hv = h_v + (long long)rec.y * HID;
      const float* ea = edge_attr + (long long)rec.x * EDIM;
      #pragma unroll
      for (int i = 0; i < 6; ++i) {
        const int c0 = w * 48 + i * 8;
        const float* src = (c0 < HID) ? (hv + c0) : (ea + (c0 - HID));
        float4 v0 = *(const float4*)(src);
        float4 v1 = *(const float4*)(src + 4);
        write8(&A[lane * A1_ST + c0], v0, v1);
      }
    }
    __syncthreads();                           // sync1: A + dstl ready

    f32x4 acc[4][2];
    #pragma unroll
    for (int mi = 0; mi < 4; ++mi)
      #pragma unroll
      for (int ni = 0; ni < 2; ++ni) acc[mi][ni] = (f32x4){0.f, 0.f, 0.f, 0.f};

    #pragma unroll
    for (int ks = 0; ks < 6; ++ks) {
      const int kk = ks * 32 + (lane >> 4) * 8;
      bf16x8 a[4];
      #pragma unroll
      for (int mi = 0; mi < 4; ++mi)
        a[mi] = *(const bf16x8*)&A[(mi * 16 + (lane & 15)) * A1_ST + kk];
      #pragma unroll
      for (int mi = 0; mi < 4; ++mi) {
        acc[mi][0] = __builtin_amdgcn_mfma_f32_16x16x32_bf16(a[mi], B[ks][0], acc[mi][0], 0, 0, 0);
        acc[mi][1] = __builtin_amdgcn_mfma_f32_16x16x32_bf16(a[mi], B[ks][1], acc[mi][1], 0, 0, 0);
      }
    }
    __syncthreads();                           // sync2: all A reads done

    float* Mw = M + w * MW_SZ;                 // per-wave private region
    {
      const int cl = lane & 15;
      const int r0 = (lane >> 4) << 2;
      #pragma unroll
      for (int mi = 0; mi < 4; ++mi)
        #pragma unroll
        for (int ni = 0; ni < 2; ++ni)
          #pragma unroll
          for (int r = 0; r < 4; ++r)
            Mw[(mi * 16 + r0 + r) * MW_ST + cl + ni * 16] =
                fmaxf(acc[mi][ni][r], 0.f);
    }
    asm volatile("s_waitcnt lgkmcnt(0)" ::: "memory");  // own writes visible

    { // same-wave segment-sum: 2 lanes/col over wave's own 32 cols
      const int c = lane & 31;
      const int h = lane >> 5;
      const int gcol = w * 32 + c;
      const int r0 = h * 32;
      int cur = dstl[r0];
      float s2 = 0.f;
      #pragma unroll 4
      for (int r = r0; r < r0 + 32; ++r) {
        const int d = dstl[r];
        if (d != cur) {
          atomicAdd(&agg[(long long)cur * HID + gcol], s2);
          s2 = 0.f; cur = d;
        }
        s2 += Mw[r * MW_ST + c];
      }
      atomicAdd(&agg[(long long)cur * HID + gcol], s2);
    }
    __syncthreads();                           // sync3: next stage may overwrite
  }
}

// ---- K2 (NEW, zero-barrier): a-frags loaded DIRECTLY from global h_e
//      (each element consumed exactly once -> staging was pure overhead).
//      M per-wave private; epilogue reads ei directly (L1-hot). -------------
#define MW2_ST 33
#define MW2_SZ (64 * MW2_ST)

__global__ __launch_bounds__(256, 3) void k2_mfma(
    const float* __restrict__ h_e, const int* __restrict__ ei,
    const float* __restrict__ W_h, const float* __restrict__ agg,
    float* __restrict__ h_e_new)
{
  __shared__ __align__(16) float M[4 * MW2_SZ];            // 33792 B only
  const int t = threadIdx.x, lane = t & 63, w = t >> 6;

  bf16x8 B[4][2];
  load_w<4>(W_h, w * 32, lane, B);

  const int arow = lane & 15;          // a-frag row within 16-row block
  const int acol = (lane >> 4) * 8;    // a-frag k-offset within 32

  for (int tile = blockIdx.x; tile < NTILES; tile += gridDim.x) {
    const int ebase = tile * 64;

    f32x4 acc[4][2];
    #pragma unroll
    for (int mi = 0; mi < 4; ++mi)
      #pragma unroll
      for (int ni = 0; ni < 2; ++ni) acc[mi][ni] = (f32x4){0.f, 0.f, 0.f, 0.f};

    #pragma unroll
    for (int ks = 0; ks < 4; ++ks) {
      const int kk = ks * 32 + acol;
      #pragma unroll
      for (int mi = 0; mi < 4; ++mi) {
        const float* p = h_e + (long long)(ebase + mi * 16 + arow) * HID + kk;
        const float4 u0 = *(const float4*)p;
        const float4 u1 = *(const float4*)(p + 4);
        const bf16x8 a = cvt8(u0, u1);
        acc[mi][0] = __builtin_amdgcn_mfma_f32_16x16x32_bf16(a, B[ks][0], acc[mi][0], 0, 0, 0);
        acc[mi][1] = __builtin_amdgcn_mfma_f32_16x16x32_bf16(a, B[ks][1], acc[mi][1], 0, 0, 0);
      }
    }

    float* Mw = M + w * MW2_SZ;               // per-wave private
    {
      const int cl = lane & 15;
      const int r0 = (lane >> 4) << 2;
      #pragma unroll
      for (int mi = 0; mi < 4; ++mi)
        #pragma unroll
        for (int ni = 0; ni < 2; ++ni)
          #pragma unroll
          for (int r = 0; r < 4; ++r)
            Mw[(mi * 16 + r0 + r) * MW2_ST + cl + ni * 16] = acc[mi][ni][r];
    }
    asm volatile("s_waitcnt lgkmcnt(0)" ::: "memory");  // own Mw writes visible

    { // per-wave epilogue: wave's 32 cols of all 64 rows, float4-vectorized
      const int q = lane & 7;                 // quad within wave's 32 cols
      const int colf = w * 32 + q * 4;        // global col (floats)
      #pragma unroll
      for (int it = 0; it < 8; ++it) {
        const int row = it * 8 + (lane >> 3);
        const int grow = ebase + row;
        const int s = ei[grow];               // direct (256B region, L1-hot)
        const float4 mm = *(const float4*)&Mw[row * MW2_ST + q * 4];
        const float4 ag = *(const float4*)(agg + (long long)s * HID + colf);
        float4 r;
        r.x = fmaxf(mm.x + ag.x, 0.f);
        r.y = fmaxf(mm.y + ag.y, 0.f);
        r.z = fmaxf(mm.z + ag.z, 0.f);
        r.w = fmaxf(mm.w + ag.w, 0.f);
        *(float4*)(h_e_new + (long long)grow * HID + colf) = r;
      }
    }
    // no barriers anywhere: waves fully independent; Mw reuse is same-wave
    // ordered (epilogue loads are data-dependencies of the stores above).
  }
}

// ---- K3 (R11-proven): h_v_new = relu([h_v|agg] @ W_o + b_o), bf16 MFMA. ----
#define A3_ST 264   // 256 cols + pad (mult of 8)
#define M3_ST 132
#define K3_SMEM (64 * A3_ST * 2)    // 33792 B == 64*M3_ST*4 (overlay)

__global__ __launch_bounds__(256, 3) void k3_mfma(
    const float* __restrict__ h_v, const float* __restrict__ W_o,
    const float* __restrict__ b_o, float* __restrict__ agg)
{
  __shared__ __align__(16) char smem[K3_SMEM];
  unsigned short* A = (unsigned short*)smem;
  float* M = (float*)smem;

  const int t = threadIdx.x, lane = t & 63, w = t >> 6;

  bf16x8 B[8][2];
  load_w<8>(W_o, w * 32, lane, B);

  const int tile = blockIdx.x;              // one tile per block (313 blocks)
  const int rbase = tile * 64;
  const int grow0 = rbase + lane;
  const int rsafe = (grow0 < NATOMS) ? grow0 : 0;
  {
    const float* hv = h_v + (long long)rsafe * HID;
    const float* ag = agg + (long long)rsafe * HID;
    #pragma unroll
    for (int i = 0; i < 8; ++i) {
      const int c0 = w * 64 + i * 8;        // wave covers 64 cols of 256
      const float* src = (c0 < HID) ? (hv + c0) : (ag + (c0 - HID));
      float4 v0 = *(const float4*)(src);
      float4 v1 = *(const float4*)(src + 4);
      write8(&A[lane * A3_ST + c0], v0, v1);
    }
  }
  __syncthreads();                          // A ready (all agg rows staged)

  f32x4 acc[4][2];
  #pragma unroll
  for (int mi = 0; mi < 4; ++mi)
    #pragma unroll
    for (int ni = 0; ni < 2; ++ni) acc[mi][ni] = (f32x4){0.f, 0.f, 0.f, 0.f};

  #pragma unroll
  for (int ks = 0; ks < 8; ++ks) {
    const int kk = ks * 32 + (lane >> 4) * 8;
    bf16x8 a[4];
    #pragma unroll
    for (int mi = 0; mi < 4; ++mi)
      a[mi] = *(const bf16x8*)&A[(mi * 16 + (lane & 15)) * A3_ST + kk];
    #pragma unroll
    for (int mi = 0; mi < 4; ++mi) {
      acc[mi][0] = __builtin_amdgcn_mfma_f32_16x16x32_bf16(a[mi], B[ks][0], acc[mi][0], 0, 0, 0);
      acc[mi][1] = __builtin_amdgcn_mfma_f32_16x16x32_bf16(a[mi], B[ks][1], acc[mi][1], 0, 0, 0);
    }
  }
  __syncthreads();                          // all A reads done before M overlay

  { // acc -> f32 LDS tile
    const int colb = w * 32 + (lane & 15);
    const int r0 = (lane >> 4) << 2;
    #pragma unroll
    for (int mi = 0; mi < 4; ++mi)
      #pragma unroll
      for (int ni = 0; ni < 2; ++ni)
        #pragma unroll
        for (int r = 0; r < 4; ++r)
          M[(mi * 16 + r0 + r) * M3_ST + colb + ni * 16] = acc[mi][ni][r];
  }
  __syncthreads();

  { // vectorized epilogue: + b_o, relu, f32 stores (guarded)
    const int quad = t & 31;
    const int rb = t >> 5;
    const float4 bo = ((const float4*)b_o)[quad];
    #pragma unroll
    for (int it = 0; it < 8; ++it) {
      const int row = rb + it * 8;
      const int grow = rbase + row;
      if (grow < NATOMS) {
        const float4 mm = *(const float4*)&M[row * M3_ST + quad * 4];
        float4 r;
        r.x = fmaxf(mm.x + bo.x, 0.f);
        r.y = fmaxf(mm.y + bo.y, 0.f);
        r.z = fmaxf(mm.z + bo.z, 0.f);
        r.w = fmaxf(mm.w + bo.w, 0.f);
        *(float4*)(agg + (long long)grow * HID + quad * 4) = r;
      }
    }
  }
}

// -----------------------------------------------------------------------------
extern "C" void kernel_launch(void* const* d_in, const int* in_sizes, int n_in,
                              void* d_out, int out_size, void* d_ws, size_t ws_size,
                              hipStream_t stream) {
  const float* h_v       = (const float*)d_in[0];
  const int*   ei        = (const int*)d_in[1];   // [2, NEDGES] int32 on device
  const float* edge_attr = (const float*)d_in[2];
  const float* h_e       = (const float*)d_in[3];
  const float* W_i       = (const float*)d_in[4];
  const float* W_h       = (const float*)d_in[5];
  const float* W_o       = (const float*)d_in[6];
  const float* b_o       = (const float*)d_in[7];
  const int*   dst       = ei + NEDGES;

  float* out       = (float*)d_out;
  float* agg       = out;                               // h_v_new region
  float* he_region = out + (size_t)NATOMS * HID;        // h_e_new region
  float* h_e_new   = he_region;

  // scratch inside h_e_new region (consumed by k1; k2 overwrites afterwards)
  int4* esd   = (int4*)he_region;                       // 640000 * 16B
  int*  meta  = (int*)(esd + NEDGES);
  int*  hist  = meta;                                   // 20000
  int*  bsum  = meta + NATOMS;                          // 80
  int*  cursor= bsum + SCAN_BLOCKS;                     // 20000
  int*  rank  = cursor + NATOMS;                        // 640000

  hipMemsetAsync(hist, 0, NATOMS * sizeof(int), stream);

  k_hist<<<(NEDGES + 255) / 256, 256, 0, stream>>>(dst, hist, (float4*)agg, rank);
  k_scan1<<<SCAN_BLOCKS, 256, 0, stream>>>(hist, bsum);
  k_scan3<<<SCAN_BLOCKS, 256, 0, stream>>>(hist, bsum, cursor);
  k_fill<<<(NEDGES + 255) / 256, 256, 0, stream>>>(ei, cursor, rank, esd);

  k1_fused<<<1024, 256, 0, stream>>>(h_v, edge_attr, W_i, esd, agg);
  k2_mfma<<<768, 256, 0, stream>>>(h_e, ei, W_h, agg, h_e_new);
  k3_mfma<<<K3TILES, 256, 0, stream>>>(h_v, W_o, b_o, agg);
}

// Round 21
// 342.821 us; speedup vs baseline: 1.1744x; 1.1744x over previous
//
#include <hip/hip_runtime.h>
#include <hip/hip_bf16.h>

#define NATOMS 20000
#define NEDGES 640000
#define HID 128
#define EDIM 64
#define NTILES (NEDGES / 64)   // 10000
#define K3TILES ((NATOMS + 63) / 64)  // 313

#define SCAN_BLOCKS 80
#define SCAN_CHUNK 250         // 80*250 = 20000

typedef __attribute__((ext_vector_type(8))) short bf16x8;
typedef __attribute__((ext_vector_type(4))) float f32x4;

__device__ __forceinline__ unsigned short f2b(float f) {
  union { float f; unsigned u; } c; c.f = f;
  unsigned u = c.u + 0x7fff + ((c.u >> 16) & 1);   // RNE (finite data)
  return (unsigned short)(u >> 16);
}

// pack 8 f32 -> 8 bf16 (HW v_cvt_pk_bf16_f32) and write 16B to LDS
__device__ __forceinline__ void write8(unsigned short* p, float4 a, float4 b) {
  union { __hip_bfloat162 h[4]; uint4 q; } pk;
  pk.h[0] = __float22bfloat162_rn(make_float2(a.x, a.y));
  pk.h[1] = __float22bfloat162_rn(make_float2(a.z, a.w));
  pk.h[2] = __float22bfloat162_rn(make_float2(b.x, b.y));
  pk.h[3] = __float22bfloat162_rn(make_float2(b.z, b.w));
  *(uint4*)p = pk.q;
}

// Per-wave W fragments: wave owns cols [wbase, wbase+32). W fp32 [K][128].
template <int KSTEPS>
__device__ __forceinline__ void load_w(const float* __restrict__ W, int wbase,
                                       int lane, bf16x8 B[KSTEPS][2]) {
  const int col0 = wbase + (lane & 15);
  const int krow0 = (lane >> 4) * 8;
  #pragma unroll
  for (int ks = 0; ks < KSTEPS; ++ks)
    #pragma unroll
    for (int ni = 0; ni < 2; ++ni) {
      const float* p = W + (long long)(ks * 32 + krow0) * HID + col0 + ni * 16;
      bf16x8 b;
      #pragma unroll
      for (int j = 0; j < 8; ++j) b[j] = (short)f2b(p[(long long)j * HID]);
      B[ks][ni] = b;
    }
}

// ---------------- CSR build (rank-based; k_fill has NO atomics) --------------
__global__ __launch_bounds__(256) void k_hist(const int* __restrict__ dst,
                                              int* __restrict__ hist,
                                              float4* __restrict__ aggz,
                                              int* __restrict__ rank) {
  int e = blockIdx.x * 256 + threadIdx.x;
  if (e < NEDGES) {
    aggz[e] = make_float4(0.f, 0.f, 0.f, 0.f);
    rank[e] = atomicAdd(&hist[dst[e]], 1);
  }
}

// partial sums per 250-chunk
__global__ __launch_bounds__(256) void k_scan1(const int* __restrict__ hist,
                                               int* __restrict__ bsum) {
  __shared__ int sh[256];
  const int b = blockIdx.x, t = threadIdx.x;
  const int lo = b * SCAN_CHUNK;
  int s = 0;
  for (int i = t; i < SCAN_CHUNK; i += 256) s += hist[lo + i];
  sh[t] = s; __syncthreads();
  for (int off = 128; off > 0; off >>= 1) {
    if (t < off) sh[t] += sh[t + off];
    __syncthreads();
  }
  if (t == 0) bsum[b] = sh[0];
}

// per-block: base = sum(bsum[0..b)) computed redundantly; local scan -> cursor
__global__ __launch_bounds__(256) void k_scan3(const int* __restrict__ hist,
                                               const int* __restrict__ bsum,
                                               int* __restrict__ cursor) {
  __shared__ int sh[256];
  const int b = blockIdx.x, t = threadIdx.x;
  const int lo = b * SCAN_CHUNK;
  int v = (t < SCAN_BLOCKS && t < b) ? bsum[t] : 0;
  sh[t] = v; __syncthreads();
  for (int off = 128; off > 0; off >>= 1) {
    if (t < off) sh[t] += sh[t + off];
    __syncthreads();
  }
  const int blockoff = sh[0];
  __syncthreads();
  sh[t] = (t < SCAN_CHUNK) ? hist[lo + t] : 0;
  __syncthreads();
  for (int off = 1; off < 256; off <<= 1) {
    int u = (t >= off) ? sh[t - off] : 0;
    __syncthreads();
    sh[t] += u;
    __syncthreads();
  }
  if (t < SCAN_CHUNK) cursor[lo + t] = blockoff + ((t == 0) ? 0 : sh[t - 1]);
}

// fill dst-sorted packed (edge, src, dst) records — atomic-free
__global__ __launch_bounds__(256) void k_fill(const int* __restrict__ ei,
                                              const int* __restrict__ cursor,
                                              const int* __restrict__ rank,
                                              int4* __restrict__ esd) {
  int e = blockIdx.x * 256 + threadIdx.x;
  if (e < NEDGES) {
    const int s = ei[e];
    const int d = ei[NEDGES + e];
    const int p = cursor[d] + rank[e];
    esd[p] = make_int4(e, s, d, 0);
  }
}

// ---- K1 fused (R11-proven): per sorted-edge tile, m = relu([h_v[src]|ea]@W_i)
//      in LDS, per-WAVE private M tile -> same-wave segment-sum -> atomics. --
#define A1_ST 200   // bf16 staging row stride
#define MW_ST 33    // per-wave f32 M stride ([64][33])
#define MW_SZ (64 * MW_ST)
#define K1_SMEM (4 * MW_SZ * 4)     // 33792 B (A 25600 B overlaid)

__global__ __launch_bounds__(256, 3) void k1_fused(
    const float* __restrict__ h_v, const float* __restrict__ edge_attr,
    const float* __restrict__ W_i, const int4* __restrict__ esd,
    float* __restrict__ agg)
{
  __shared__ __align__(16) char smem[K1_SMEM];
  unsigned short* A = (unsigned short*)smem;
  float* M = (float*)smem;
  __shared__ int dstl[64];

  const int t = threadIdx.x, lane = t & 63, w = t >> 6;

  bf16x8 B[6][2];
  load_w<6>(W_i, w * 32, lane, B);

  for (int tile = blockIdx.x; tile < NTILES; tile += gridDim.x) {
    const int ebase = tile * 64;
    const int4 rec = esd[ebase + lane];        // (e, src, dst, _) coalesced
    if (w == 0) dstl[lane] = rec.z;
    {
      const float* hv = h_v + (long long)rec.y * HID;
      const float* ea = edge_attr + (long long)rec.x * EDIM;
      #pragma unroll
      for (int i = 0; i < 6; ++i) {
        const int c0 = w * 48 + i * 8;
        const float* src = (c0 < HID) ? (hv + c0) : (ea + (c0 - HID));
        float4 v0 = *(const float4*)(src);
        float4 v1 = *(const float4*)(src + 4);
        write8(&A[lane * A1_ST + c0], v0, v1);
      }
    }
    __syncthreads();                           // sync1: A + dstl ready

    f32x4 acc[4][2];
    #pragma unroll
    for (int mi = 0; mi < 4; ++mi)
      #pragma unroll
      for (int ni = 0; ni < 2; ++ni) acc[mi][ni] = (f32x4){0.f, 0.f, 0.f, 0.f};

    #pragma unroll
    for (int ks = 0; ks < 6; ++ks) {
      const int kk = ks * 32 + (lane >> 4) * 8;
      bf16x8 a[4];
      #pragma unroll
      for (int mi = 0; mi < 4; ++mi)
        a[mi] = *(const bf16x8*)&A[(mi * 16 + (lane & 15)) * A1_ST + kk];
      #pragma unroll
      for (int mi = 0; mi < 4; ++mi) {
        acc[mi][0] = __builtin_amdgcn_mfma_f32_16x16x32_bf16(a[mi], B[ks][0], acc[mi][0], 0, 0, 0);
        acc[mi][1] = __builtin_amdgcn_mfma_f32_16x16x32_bf16(a[mi], B[ks][1], acc[mi][1], 0, 0, 0);
      }
    }
    __syncthreads();                           // sync2: all A reads done

    float* Mw = M + w * MW_SZ;                 // per-wave private region
    {
      const int cl = lane & 15;
      const int r0 = (lane >> 4) << 2;
      #pragma unroll
      for (int mi = 0; mi < 4; ++mi)
        #pragma unroll
        for (int ni = 0; ni < 2; ++ni)
          #pragma unroll
          for (int r = 0; r < 4; ++r)
            Mw[(mi * 16 + r0 + r) * MW_ST + cl + ni * 16] =
                fmaxf(acc[mi][ni][r], 0.f);
    }
    asm volatile("s_waitcnt lgkmcnt(0)" ::: "memory");  // own writes visible

    { // same-wave segment-sum: 2 lanes/col over wave's own 32 cols
      const int c = lane & 31;
      const int h = lane >> 5;
      const int gcol = w * 32 + c;
      const int r0 = h * 32;
      int cur = dstl[r0];
      float s2 = 0.f;
      #pragma unroll 4
      for (int r = r0; r < r0 + 32; ++r) {
        const int d = dstl[r];
        if (d != cur) {
          atomicAdd(&agg[(long long)cur * HID + gcol], s2);
          s2 = 0.f; cur = d;
        }
        s2 += Mw[r * MW_ST + c];
      }
      atomicAdd(&agg[(long long)cur * HID + gcol], s2);
    }
    __syncthreads();                           // sync3: next stage may overwrite
  }
}

// ---- K2 (R17-proven): LDS-staged A, per-wave-private M, 2 barriers/tile. ----
#define A2_ST 136
#define MW2_ST 33
#define MW2_SZ (64 * MW2_ST)

__global__ __launch_bounds__(256, 3) void k2_mfma(
    const float* __restrict__ h_e, const int* __restrict__ ei,
    const float* __restrict__ W_h, const float* __restrict__ agg,
    float* __restrict__ h_e_new)
{
  __shared__ __align__(16) unsigned short A[64 * A2_ST];   // 17408 B
  __shared__ __align__(16) float M[4 * MW2_SZ];            // 33792 B
  __shared__ int srcl[2][64];

  const int t = threadIdx.x, lane = t & 63, w = t >> 6;

  bf16x8 B[4][2];
  load_w<4>(W_h, w * 32, lane, B);

  int p = 0;
  for (int tile = blockIdx.x; tile < NTILES; tile += gridDim.x, p ^= 1) {
    const int ebase = tile * 64;
    {
      if (w == 0) srcl[p][lane] = ei[ebase + lane];
      const float* he = h_e + (long long)(ebase + lane) * HID;
      #pragma unroll
      for (int i = 0; i < 4; ++i) {
        const int c0 = w * 32 + i * 8;
        float4 v0 = *(const float4*)(he + c0);
        float4 v1 = *(const float4*)(he + c0 + 4);
        write8(&A[lane * A2_ST + c0], v0, v1);
      }
    }
    __syncthreads();                          // sync1: A + srcl[p] ready

    f32x4 acc[4][2];
    #pragma unroll
    for (int mi = 0; mi < 4; ++mi)
      #pragma unroll
      for (int ni = 0; ni < 2; ++ni) acc[mi][ni] = (f32x4){0.f, 0.f, 0.f, 0.f};

    #pragma unroll
    for (int ks = 0; ks < 4; ++ks) {
      const int kk = ks * 32 + (lane >> 4) * 8;
      bf16x8 a[4];
      #pragma unroll
      for (int mi = 0; mi < 4; ++mi)
        a[mi] = *(const bf16x8*)&A[(mi * 16 + (lane & 15)) * A2_ST + kk];
      #pragma unroll
      for (int mi = 0; mi < 4; ++mi) {
        acc[mi][0] = __builtin_amdgcn_mfma_f32_16x16x32_bf16(a[mi], B[ks][0], acc[mi][0], 0, 0, 0);
        acc[mi][1] = __builtin_amdgcn_mfma_f32_16x16x32_bf16(a[mi], B[ks][1], acc[mi][1], 0, 0, 0);
      }
    }
    __syncthreads();                          // sync2: all A reads done

    float* Mw = M + w * MW2_SZ;               // per-wave private
    {
      const int cl = lane & 15;
      const int r0 = (lane >> 4) << 2;
      #pragma unroll
      for (int mi = 0; mi < 4; ++mi)
        #pragma unroll
        for (int ni = 0; ni < 2; ++ni)
          #pragma unroll
          for (int r = 0; r < 4; ++r)
            Mw[(mi * 16 + r0 + r) * MW2_ST + cl + ni * 16] = acc[mi][ni][r];
    }
    asm volatile("s_waitcnt lgkmcnt(0)" ::: "memory");  // own Mw writes visible

    { // per-wave epilogue: wave's 32 cols of all 64 rows, float4-vectorized
      const int q = lane & 7;                 // quad within wave's 32 cols
      const int colf = w * 32 + q * 4;        // global col (floats)
      #pragma unroll
      for (int it = 0; it < 8; ++it) {
        const int row = it * 8 + (lane >> 3);
        const int grow = ebase + row;
        const int s = srcl[p][row];
        const float4 mm = *(const float4*)&Mw[row * MW2_ST + q * 4];
        const float4 ag = *(const float4*)(agg + (long long)s * HID + colf);
        float4 r;
        r.x = fmaxf(mm.x + ag.x, 0.f);
        r.y = fmaxf(mm.y + ag.y, 0.f);
        r.z = fmaxf(mm.z + ag.z, 0.f);
        r.w = fmaxf(mm.w + ag.w, 0.f);
        *(float4*)(h_e_new + (long long)grow * HID + colf) = r;
      }
    }
  }
}

// ---- K3 (R11-proven): h_v_new = relu([h_v|agg] @ W_o + b_o), bf16 MFMA. ----
#define A3_ST 264   // 256 cols + pad (mult of 8)
#define M3_ST 132
#define K3_SMEM (64 * A3_ST * 2)    // 33792 B == 64*M3_ST*4 (overlay)

__global__ __launch_bounds__(256, 3) void k3_mfma(
    const float* __restrict__ h_v, const float* __restrict__ W_o,
    const float* __restrict__ b_o, float* __restrict__ agg)
{
  __shared__ __align__(16) char smem[K3_SMEM];
  unsigned short* A = (unsigned short*)smem;
  float* M = (float*)smem;

  const int t = threadIdx.x, lane = t & 63, w = t >> 6;

  bf16x8 B[8][2];
  load_w<8>(W_o, w * 32, lane, B);

  const int tile = blockIdx.x;              // one tile per block (313 blocks)
  const int rbase = tile * 64;
  const int grow0 = rbase + lane;
  const int rsafe = (grow0 < NATOMS) ? grow0 : 0;
  {
    const float* hv = h_v + (long long)rsafe * HID;
    const float* ag = agg + (long long)rsafe * HID;
    #pragma unroll
    for (int i = 0; i < 8; ++i) {
      const int c0 = w * 64 + i * 8;        // wave covers 64 cols of 256
      const float* src = (c0 < HID) ? (hv + c0) : (ag + (c0 - HID));
      float4 v0 = *(const float4*)(src);
      float4 v1 = *(const float4*)(src + 4);
      write8(&A[lane * A3_ST + c0], v0, v1);
    }
  }
  __syncthreads();                          // A ready (all agg rows staged)

  f32x4 acc[4][2];
  #pragma unroll
  for (int mi = 0; mi < 4; ++mi)
    #pragma unroll
    for (int ni = 0; ni < 2; ++ni) acc[mi][ni] = (f32x4){0.f, 0.f, 0.f, 0.f};

  #pragma unroll
  for (int ks = 0; ks < 8; ++ks) {
    const int kk = ks * 32 + (lane >> 4) * 8;
    bf16x8 a[4];
    #pragma unroll
    for (int mi = 0; mi < 4; ++mi)
      a[mi] = *(const bf16x8*)&A[(mi * 16 + (lane & 15)) * A3_ST + kk];
    #pragma unroll
    for (int mi = 0; mi < 4; ++mi) {
      acc[mi][0] = __builtin_amdgcn_mfma_f32_16x16x32_bf16(a[mi], B[ks][0], acc[mi][0], 0, 0, 0);
      acc[mi][1] = __builtin_amdgcn_mfma_f32_16x16x32_bf16(a[mi], B[ks][1], acc[mi][1], 0, 0, 0);
    }
  }
  __syncthreads();                          // all A reads done before M overlay

  { // acc -> f32 LDS tile
    const int colb = w * 32 + (lane & 15);
    const int r0 = (lane >> 4) << 2;
    #pragma unroll
    for (int mi = 0; mi < 4; ++mi)
      #pragma unroll
      for (int ni = 0; ni < 2; ++ni)
        #pragma unroll
        for (int r = 0; r < 4; ++r)
          M[(mi * 16 + r0 + r) * M3_ST + colb + ni * 16] = acc[mi][ni][r];
  }
  __syncthreads();

  { // vectorized epilogue: + b_o, relu, f32 stores (guarded)
    const int quad = t & 31;
    const int rb = t >> 5;
    const float4 bo = ((const float4*)b_o)[quad];
    #pragma unroll
    for (int it = 0; it < 8; ++it) {
      const int row = rb + it * 8;
      const int grow = rbase + row;
      if (grow < NATOMS) {
        const float4 mm = *(const float4*)&M[row * M3_ST + quad * 4];
        float4 r;
        r.x = fmaxf(mm.x + bo.x, 0.f);
        r.y = fmaxf(mm.y + bo.y, 0.f);
        r.z = fmaxf(mm.z + bo.z, 0.f);
        r.w = fmaxf(mm.w + bo.w, 0.f);
        *(float4*)(agg + (long long)grow * HID + quad * 4) = r;
      }
    }
  }
}

// -----------------------------------------------------------------------------
extern "C" void kernel_launch(void* const* d_in, const int* in_sizes, int n_in,
                              void* d_out, int out_size, void* d_ws, size_t ws_size,
                              hipStream_t stream) {
  const float* h_v       = (const float*)d_in[0];
  const int*   ei        = (const int*)d_in[1];   // [2, NEDGES] int32 on device
  const float* edge_attr = (const float*)d_in[2];
  const float* h_e       = (const float*)d_in[3];
  const float* W_i       = (const float*)d_in[4];
  const float* W_h       = (const float*)d_in[5];
  const float* W_o       = (const float*)d_in[6];
  const float* b_o       = (const float*)d_in[7];
  const int*   dst       = ei + NEDGES;

  float* out       = (float*)d_out;
  float* agg       = out;                               // h_v_new region
  float* he_region = out + (size_t)NATOMS * HID;        // h_e_new region
  float* h_e_new   = he_region;

  // scratch inside h_e_new region (consumed by k1; k2 overwrites afterwards)
  int4* esd   = (int4*)he_region;                       // 640000 * 16B
  int*  meta  = (int*)(esd + NEDGES);
  int*  hist  = meta;                                   // 20000
  int*  bsum  = meta + NATOMS;                          // 80
  int*  cursor= bsum + SCAN_BLOCKS;                     // 20000
  int*  rank  = cursor + NATOMS;                        // 640000

  hipMemsetAsync(hist, 0, NATOMS * sizeof(int), stream);

  k_hist<<<(NEDGES + 255) / 256, 256, 0, stream>>>(dst, hist, (float4*)agg, rank);
  k_scan1<<<SCAN_BLOCKS, 256, 0, stream>>>(hist, bsum);
  k_scan3<<<SCAN_BLOCKS, 256, 0, stream>>>(hist, bsum, cursor);
  k_fill<<<(NEDGES + 255) / 256, 256, 0, stream>>>(ei, cursor, rank, esd);

  k1_fused<<<1024, 256, 0, stream>>>(h_v, edge_attr, W_i, esd, agg);
  k2_mfma<<<768, 256, 0, stream>>>(h_e, ei, W_h, agg, h_e_new);
  k3_mfma<<<K3TILES, 256, 0, stream>>>(h_v, W_o, b_o, agg);
}